// Round 15
// baseline (39.593 us; speedup 1.0000x reference)
//
#include <hip/hip_runtime.h>

#define NB 4
#define LL 8192
#define DD 1024
#define CHUNK 64
#define NT (LL / CHUNK)   // 128 tiles per batch
#define NF (NB * NT)      // 512 blocks
#define EPSV 1e-4f
#define WCUT 1e-7f

typedef float vf2 __attribute__((ext_vector_type(2)));   // clang vector: OK for
                                                         // __builtin_nontemporal_store

// ONE kernel, no cross-block sync. 512 threads/block, thread = 2 d-columns (vf2).
// Block (b, tile T of 64 outputs):
//  1. redundant full-batch mask prefix (32 KB, L2-resident) -> s_excl[] at
//     16-element granularity.
//  2. wave 0 preps own chunk idx/p; wave 1 (concurrently) builds warm-up:
//     suffix products of a=1-p over chunk T-1, ballot-finds the LATEST l* with
//     S_incl(l*) <= WCUT (exists whenever the chunk holds position 0: p0=1),
//     folds positions l*..l0-1 into per-row weights w_r (LDS atomicAdd).
//     Truncation error <= WCUT * |y| ~ 5e-7 << 0.107 threshold.
//  3. carry = sum_r w_r * x_r (independent vf2 FMAs over ~10 contiguous rows),
//     then the 64-step own-chunk EMA, nontemporal vf2 stores.
//  Fallback (no cut in chunk T-1; adversarial-safe, exact): chunk-walk + ring.
// XCD-contiguous swizzle keeps neighbor tiles (shared warm-up rows) on one L2.
__global__ __launch_bounds__(512) void k_one(const float* __restrict__ hid,
                                             const void* __restrict__ mask_raw,
                                             const float* __restrict__ bprob,
                                             float* __restrict__ out) {
    const int blk0 = blockIdx.x;
    const int f = (blk0 & 7) * (NF / 8) + (blk0 >> 3);   // 512 = 8 XCDs x 64
    const int b = f >> 7;                 // NT = 128
    const int T = f & (NT - 1);
    const int l0 = T * CHUNK;
    const int tid = threadIdx.x;          // 512 threads
    const int lane = tid & 63, wv = tid >> 6;   // 8 waves

    __shared__ int   s_viol;
    __shared__ int   s_wsum[8];
    __shared__ int   s_excl[512];         // boundaries in [0, 16*tid) of this batch
    __shared__ int   s_i[2][CHUNK];
    __shared__ float s_pv[2][CHUNK];
    __shared__ float s_w[CHUNK];
    __shared__ int   s_r0w, s_nrw, s_fb, s_ls;

    if (tid == 0) { s_viol = 0; s_fb = 0; s_nrw = 0; }
    if (tid < CHUNK) s_w[tid] = 0.f;
    __syncthreads();
    // ---- mask dtype detect: int32 little-endian [0/1,0,0,0] vs uint8 (first 2 KB)
    {
        unsigned int w = ((const unsigned int*)mask_raw)[tid];
        if ((w & 0xFFFFFF00u) != 0u || (w & 0xFFu) > 1u) atomicOr(&s_viol, 1);
    }
    __syncthreads();
    const bool is_int = (s_viol == 0);

    // ---- full-batch mask prefix: 512 threads x 16 elems
    const int e0 = b * LL + tid * 16;
    int s = 0;
    if (is_int) {
        const int4* mi = (const int4*)((const int*)mask_raw + e0);
        #pragma unroll
        for (int k = 0; k < 4; ++k) { int4 q = mi[k]; s += q.x + q.y + q.z + q.w; }
    } else {
        const unsigned int* mb = (const unsigned int*)((const unsigned char*)mask_raw + e0);
        #pragma unroll
        for (int k = 0; k < 4; ++k) s += (int)((mb[k] * 0x01010101u) >> 24);
    }
    int v = s;
    #pragma unroll
    for (int off = 1; off < 64; off <<= 1) {
        int u = __shfl_up(v, off, 64);
        if (lane >= off) v += u;
    }
    if (lane == 63) s_wsum[wv] = v;
    __syncthreads();
    int wexcl = 0;
    #pragma unroll
    for (int i = 0; i < 8; ++i) if (i < wv) wexcl += s_wsum[i];
    s_excl[tid] = wexcl + (v - s);
    __syncthreads();

    // ---- wave 0: own-chunk idx/p prep (slot 0, fast path)
    if (wv == 0) {
        int mval;
        if (is_int) mval = ((const int*)mask_raw)[b * LL + l0 + lane];
        else        mval = (int)((const unsigned char*)mask_raw)[b * LL + l0 + lane];
        int cc = mval;
        #pragma unroll
        for (int off = 1; off < 64; off <<= 1) {
            int u = __shfl_up(cc, off, 64);
            if (lane >= off) cc += u;
        }
        s_i[0][lane] = s_excl[T * 4] + cc - 1;
        const int l = l0 + lane;
        float pv = bprob[((size_t)(b * LL + l)) * 2 + 1];
        pv = fminf(fmaxf(pv, EPSV), 1.0f - EPSV);
        if (l == 0) pv = 1.0f;
        s_pv[0][lane] = pv;
    }
    // ---- wave 1: position-granular warm-up weights from chunk T-1
    if (wv == 1 && T > 0) {
        const int lw = l0 - CHUNK + lane;
        int mval;
        if (is_int) mval = ((const int*)mask_raw)[b * LL + lw];
        else        mval = (int)((const unsigned char*)mask_raw)[b * LL + lw];
        int cc = mval;
        #pragma unroll
        for (int off = 1; off < 64; off <<= 1) {
            int u = __shfl_up(cc, off, 64);
            if (lane >= off) cc += u;
        }
        const int my_idx = s_excl[(T - 1) * 4] + cc - 1;

        float pv = bprob[((size_t)(b * LL + lw)) * 2 + 1];
        pv = fminf(fmaxf(pv, EPSV), 1.0f - EPSV);
        if (lw == 0) pv = 1.0f;
        const float a = 1.f - pv;
        float P = a;                                // inclusive suffix product
        #pragma unroll
        for (int off = 1; off < 64; off <<= 1) {
            float u = __shfl_down(P, off, 64);
            if (lane < 64 - off) P *= u;
        }
        float S = __shfl_down(P, 1, 64);            // exclusive suffix product
        if (lane == 63) S = 1.f;

        const unsigned long long cut = __ballot(P <= WCUT);
        if (cut != 0ull) {
            const int lstar = 63 - __clzll(cut);    // latest pos with S_incl<=WCUT
            const int r0w   = __shfl(my_idx, lstar, 64);
            const int rlast = __shfl(my_idx, 63, 64);
            if (lane >= lstar) atomicAdd(&s_w[my_idx - r0w], pv * S);
            if (lane == 0) { s_r0w = r0w; s_nrw = rlast - r0w + 1; }
        } else {
            // rare fallback: walk whole chunks back (exact at position 0)
            float cum = __shfl(P, 0, 64);
            int ls = T - 1;
            while (ls > 0 && cum > WCUT) {
                --ls;
                const int l2 = ls * CHUNK + lane;
                float pv2 = bprob[((size_t)(b * LL + l2)) * 2 + 1];
                pv2 = fminf(fmaxf(pv2, EPSV), 1.0f - EPSV);
                if (l2 == 0) pv2 = 1.0f;
                float P2 = 1.f - pv2;
                #pragma unroll
                for (int off = 1; off < 64; off <<= 1)
                    P2 *= __shfl_xor(P2, off, 64);
                cum *= P2;
            }
            if (lane == 0) { s_fb = 1; s_ls = ls; }
        }
    }
    __syncthreads();

    const vf2* hb = (const vf2*)(hid + (size_t)b * LL * DD) + tid;
    vf2* ob = (vf2*)(out + ((size_t)b * LL + l0) * DD) + tid;

    if (!s_fb) {
        // ---- fast path: parallel weighted warm-up + own-chunk EMA (vf2)
        vf2 y = {0.f, 0.f};
        const int nrw = s_nrw;
        if (nrw > 0) {
            const vf2* hw = hb + (size_t)s_r0w * (DD / 2);
            #pragma unroll 4
            for (int r = 0; r < nrw; ++r)
                y += s_w[r] * hw[(size_t)r * (DD / 2)];
        }
        #pragma unroll 8
        for (int t = 0; t < CHUNK; ++t) {
            const float p = s_pv[0][t];
            const vf2 x = hb[(size_t)s_i[0][t] * (DD / 2)];
            y = p * x + (1.f - p) * y;
            __builtin_nontemporal_store(y, &ob[(size_t)t * (DD / 2)]);
        }
    } else {
        // ---- exact fallback: serial ring loop from s_ls (vf2)
        const int ls = s_ls;
        vf2 y = {0.f, 0.f};
        for (int c = ls; c <= T; ++c) {
            const int slot = c & 1;
            if (wv == 0) {
                const int cs = c * CHUNK;
                int mval;
                if (is_int) mval = ((const int*)mask_raw)[b * LL + cs + lane];
                else        mval = (int)((const unsigned char*)mask_raw)[b * LL + cs + lane];
                int cc = mval;
                #pragma unroll
                for (int off = 1; off < 64; off <<= 1) {
                    int u = __shfl_up(cc, off, 64);
                    if (lane >= off) cc += u;
                }
                s_i[slot][lane] = s_excl[c * 4] + cc - 1;
                const int l = cs + lane;
                float pv = bprob[((size_t)(b * LL + l)) * 2 + 1];
                pv = fminf(fmaxf(pv, EPSV), 1.0f - EPSV);
                if (l == 0) pv = 1.0f;
                s_pv[slot][lane] = pv;
            }
            __syncthreads();
            if (c < T) {
                #pragma unroll 8
                for (int t = 0; t < CHUNK; ++t) {
                    const float p = s_pv[slot][t];
                    const vf2 x = hb[(size_t)s_i[slot][t] * (DD / 2)];
                    y = p * x + (1.f - p) * y;
                }
            } else {
                #pragma unroll 8
                for (int t = 0; t < CHUNK; ++t) {
                    const float p = s_pv[slot][t];
                    const vf2 x = hb[(size_t)s_i[slot][t] * (DD / 2)];
                    y = p * x + (1.f - p) * y;
                    __builtin_nontemporal_store(y, &ob[(size_t)t * (DD / 2)]);
                }
            }
        }
    }
}

extern "C" void kernel_launch(void* const* d_in, const int* in_sizes, int n_in,
                              void* d_out, int out_size, void* d_ws, size_t ws_size,
                              hipStream_t stream) {
    const float* hid   = (const float*)d_in[0];
    const void*  mask  = d_in[1];
    const float* bprob = (const float*)d_in[2];
    float* out = (float*)d_out;

    k_one<<<NF, 512, 0, stream>>>(hid, mask, bprob, out);
}